// Round 4
// baseline (640.855 us; speedup 1.0000x reference)
//
#include <hip/hip_runtime.h>

#define F 64     // F_IN == F_OUT == 64
#define TILE 64  // nodes per tile / per fused block
#define CAP 2048 // bucket capacity (avg 1024 edges/tile, ~32 sigma headroom)
#define PADR 65  // LDS row stride: breaks power-of-2 bank strides

// ---------------------------------------------------------------------------
// R3 -> R4: drop the per-node CSR (count + 3 scans + fill, ~130 us with gaps).
// The consumer is a 64-node tile kernel, so bin edges by TILE only:
// one atomic cursor per tile, entry = (dst&63)<<17 | src packed in 4 B.
// ---------------------------------------------------------------------------
__global__ __launch_bounds__(256) void bin_kernel(
    const int* __restrict__ edge_index, int* __restrict__ tileCnt,
    unsigned* __restrict__ tileBuf, int n_edges) {
  int e = blockIdx.x * 256 + threadIdx.x;
  if (e >= n_edges) return;
  int src = edge_index[e];
  int dst = edge_index[n_edges + e];
  int tile = dst >> 6;
  int pos = atomicAdd(&tileCnt[tile], 1);
  if (pos < CAP)  // statistically never taken; guards OOB corruption
    tileBuf[(size_t)tile * CAP + pos] =
        ((unsigned)(dst & 63) << 17) | (unsigned)src;
}

// Transpose weights once: WT[k][o] = W[o][k] (32 KB, L1/L2-resident for GEMM).
__global__ __launch_bounds__(256) void transpose_w_kernel(
    const float* __restrict__ W_rel, const float* __restrict__ W_root,
    float* __restrict__ WTrel, float* __restrict__ WTroot) {
  int t = blockIdx.x * 256 + threadIdx.x;
  if (t < F * F) {
    int o = t >> 6, k = t & 63;
    WTrel[k * F + o] = W_rel[t];
    WTroot[k * F + o] = W_root[t];
  }
}

// ---------------------------------------------------------------------------
// Fused: LDS scatter-accumulate over the tile's edge bucket + GEMM + bias +
// ReLU.  Aggregation: per wave, one coalesced 64-entry bucket read; each
// entry is shfl-broadcast; all 64 lanes load x[src][lane] (one coalesced
// 256 B read, L2/L3-resident) and ds_add_f32 into agg[d][lane] (consecutive
// lanes -> 2-way bank alias, free on gfx950).  ~6 wave-instrs/edge.
// GEMM: thread (rq,oq) owns a 4x4 block; per k: 8 conflict-free ds_read_b32
// (bank = (4rq+i+k)%32, all distinct per instr) + 2 L1-resident float4 WT
// reads + 32 FMA.  LDS 2*64*65*4 = 32.5 KB -> 4 blocks/CU.
// ---------------------------------------------------------------------------
__global__ __launch_bounds__(256) void tile_gather_gemm_kernel(
    const float* __restrict__ x,
    const float* __restrict__ WTrel,   // [F][F] k-major
    const float* __restrict__ b_rel,   // [F]
    const float* __restrict__ WTroot,  // [F][F] k-major
    const int* __restrict__ tileCnt,
    const unsigned* __restrict__ tileBuf,
    float* __restrict__ out, int n_nodes) {
  __shared__ float agg[TILE * PADR];
  __shared__ float xs[TILE * PADR];

  const int t = threadIdx.x;
  const int lane = t & 63;
  const int w = t >> 6;
  const int tile = blockIdx.x;
  const int node0 = tile * TILE;

  // zero the accumulator tile
  for (int i = t; i < TILE * PADR; i += 256) agg[i] = 0.0f;

  // stage the x self-tile (row-major; scalar LDS writes, one-time)
  {
    const int r = t >> 2;             // 0..63
    const int c0 = (t & 3) * 16;      // 16 cols per thread, 4 float4 loads
    const int gi = node0 + r;
#pragma unroll
    for (int c = 0; c < 16; c += 4) {
      float4 v = make_float4(0.f, 0.f, 0.f, 0.f);
      if (gi < n_nodes) v = *(const float4*)(x + (size_t)gi * F + c0 + c);
      xs[r * PADR + c0 + c + 0] = v.x;
      xs[r * PADR + c0 + c + 1] = v.y;
      xs[r * PADR + c0 + c + 2] = v.z;
      xs[r * PADR + c0 + c + 3] = v.w;
    }
  }
  __syncthreads();

  // ---- phase 1: scatter-accumulate this tile's edges into LDS
  const int cnt = tileCnt[tile];
  const unsigned* lst = tileBuf + (size_t)tile * CAP;
  const float* xl = x + lane;
  for (int base = w * 64; base < cnt; base += 256) {
    const int m = min(64, cnt - base);
    unsigned ent = (lane < m) ? lst[base + lane] : 0u;
    if (m == 64) {
#pragma unroll 8
      for (int b = 0; b < 64; ++b) {
        const unsigned e = __shfl(ent, b, 64);
        const float v = xl[(size_t)(e & 0x1FFFFu) * F];
        atomicAdd(&agg[(e >> 17) * PADR + lane], v);
      }
    } else {
      for (int b = 0; b < m; ++b) {
        const unsigned e = __shfl(ent, b, 64);
        const float v = xl[(size_t)(e & 0x1FFFFu) * F];
        atomicAdd(&agg[(e >> 17) * PADR + lane], v);
      }
    }
  }
  __syncthreads();

  // ---- phase 2: out[r][o] = relu(b[o] + sum_k agg[r][k]*WTrel[k][o]
  //                                       + sum_k xs[r][k]*WTroot[k][o])
  const int oq = t & 15, rq = t >> 4;
  const int o0 = oq * 4, r0 = rq * 4;
  const float4 bias = *(const float4*)(b_rel + o0);
  float acc[4][4];
#pragma unroll
  for (int ri = 0; ri < 4; ++ri) {
    acc[ri][0] = bias.x; acc[ri][1] = bias.y;
    acc[ri][2] = bias.z; acc[ri][3] = bias.w;
  }
#pragma unroll 4
  for (int k = 0; k < F; ++k) {
    const float4 wr = *(const float4*)(WTrel + k * F + o0);
    const float4 wo = *(const float4*)(WTroot + k * F + o0);
    const float a0 = agg[(r0 + 0) * PADR + k], a1 = agg[(r0 + 1) * PADR + k];
    const float a2 = agg[(r0 + 2) * PADR + k], a3 = agg[(r0 + 3) * PADR + k];
    const float x0 = xs[(r0 + 0) * PADR + k], x1 = xs[(r0 + 1) * PADR + k];
    const float x2 = xs[(r0 + 2) * PADR + k], x3 = xs[(r0 + 3) * PADR + k];
    acc[0][0] += a0 * wr.x + x0 * wo.x; acc[0][1] += a0 * wr.y + x0 * wo.y;
    acc[0][2] += a0 * wr.z + x0 * wo.z; acc[0][3] += a0 * wr.w + x0 * wo.w;
    acc[1][0] += a1 * wr.x + x1 * wo.x; acc[1][1] += a1 * wr.y + x1 * wo.y;
    acc[1][2] += a1 * wr.z + x1 * wo.z; acc[1][3] += a1 * wr.w + x1 * wo.w;
    acc[2][0] += a2 * wr.x + x2 * wo.x; acc[2][1] += a2 * wr.y + x2 * wo.y;
    acc[2][2] += a2 * wr.z + x2 * wo.z; acc[2][3] += a2 * wr.w + x2 * wo.w;
    acc[3][0] += a3 * wr.x + x3 * wo.x; acc[3][1] += a3 * wr.y + x3 * wo.y;
    acc[3][2] += a3 * wr.z + x3 * wo.z; acc[3][3] += a3 * wr.w + x3 * wo.w;
  }
#pragma unroll
  for (int ri = 0; ri < 4; ++ri) {
    const int gi = node0 + r0 + ri;
    if (gi < n_nodes) {
      float4 o4;
      o4.x = fmaxf(acc[ri][0], 0.f); o4.y = fmaxf(acc[ri][1], 0.f);
      o4.z = fmaxf(acc[ri][2], 0.f); o4.w = fmaxf(acc[ri][3], 0.f);
      *(float4*)(out + (size_t)gi * F + o0) = o4;
    }
  }
}

extern "C" void kernel_launch(void* const* d_in, const int* in_sizes, int n_in,
                              void* d_out, int out_size, void* d_ws, size_t ws_size,
                              hipStream_t stream) {
  const float* x      = (const float*)d_in[0];  // [N, 64]
  const float* W_rel  = (const float*)d_in[1];  // [64, 64]
  const float* b_rel  = (const float*)d_in[2];  // [64]
  const float* W_root = (const float*)d_in[3];  // [64, 64]
  const int* edge_index = (const int*)d_in[4];  // [2, E]

  const int n_nodes = in_sizes[0] / F;
  const int n_edges = in_sizes[4] / 2;
  const int n_tiles = (n_nodes + TILE - 1) / TILE;  // 782

  // workspace: tileCnt[1024] + tileBuf[782*2048] (6.4 MB) + WT (32 KB)
  int* tileCnt      = (int*)d_ws;
  unsigned* tileBuf = (unsigned*)(tileCnt + 1024);
  float* WTrel      = (float*)(tileBuf + (size_t)n_tiles * CAP);
  float* WTroot     = WTrel + F * F;

  float* out = (float*)d_out;

  hipMemsetAsync(tileCnt, 0, (size_t)n_tiles * sizeof(int), stream);

  transpose_w_kernel<<<(F * F + 255) / 256, 256, 0, stream>>>(W_rel, W_root,
                                                              WTrel, WTroot);

  bin_kernel<<<(n_edges + 255) / 256, 256, 0, stream>>>(edge_index, tileCnt,
                                                        tileBuf, n_edges);

  tile_gather_gemm_kernel<<<n_tiles, 256, 0, stream>>>(
      x, WTrel, b_rel, WTroot, tileCnt, tileBuf, out, n_nodes);
}

// Round 5
// 472.718 us; speedup vs baseline: 1.3557x; 1.3557x over previous
//
#include <hip/hip_runtime.h>

#define F 64     // F_IN == F_OUT == 64
#define TILE 64  // nodes per tile / per fused block
#define CAP 2048 // bucket capacity (avg 1024 edges/tile)
#define PADR 65  // LDS row stride: bank = (d*65+c)%32 = (d+c)%32, d random
#define CNTP 16  // tileCnt padding: one counter per 64B line (R4 lesson:
                 // 782 counters on 49 lines -> cross-XCD atomic ping-pong)

// ---------------------------------------------------------------------------
// Bin edges by 64-node tile: entry = (dst&63)<<17 | src (src<2^17).
// ---------------------------------------------------------------------------
__global__ __launch_bounds__(256) void bin_kernel(
    const int* __restrict__ edge_index, int* __restrict__ tileCnt,
    unsigned* __restrict__ tileBuf, int n_edges) {
  int e = blockIdx.x * 256 + threadIdx.x;
  if (e >= n_edges) return;
  int src = edge_index[e];
  int dst = edge_index[n_edges + e];
  int tile = dst >> 6;
  int pos = atomicAdd(&tileCnt[tile * CNTP], 1);
  if (pos < CAP)  // statistically never taken; guards OOB corruption
    tileBuf[(size_t)tile * CAP + pos] =
        ((unsigned)(dst & 63) << 17) | (unsigned)src;
}

// Transpose weights once: WT[k][o] = W[o][k] (32 KB, L1/L2-resident in GEMM).
__global__ __launch_bounds__(256) void transpose_w_kernel(
    const float* __restrict__ W_rel, const float* __restrict__ W_root,
    float* __restrict__ WTrel, float* __restrict__ WTroot) {
  int t = blockIdx.x * 256 + threadIdx.x;
  if (t < F * F) {
    int o = t >> 6, k = t & 63;
    WTrel[k * F + o] = W_rel[t];
    WTroot[k * F + o] = W_root[t];
  }
}

// ---------------------------------------------------------------------------
// Fused: LDS scatter-accumulate + GEMM + bias + ReLU per 64-node tile.
//
// Aggregation (R4 fix): lanes = 16 edge-slots x 4 feature-quads.  Per
// 64-edge chunk: 4 entry loads (16 dwords x 4-way lane dup = 64B segments,
// NO shfl), then each lane does 4 independent float4 gathers (its edge's
// 16 features; 4 lanes cover the 256B row) and 16 ds_add_f32 into
// agg[d][c].  16 float4 loads in flight per lane -> latency hidden; exactly
// 1 LDS-atomic wave-instr per edge.
//
// GEMM: thread (rq,oq) owns a 4x4 block; per k: 8 ds_read_b32 + 2
// L1-resident float4 WT reads + 32 FMA.  LDS 2*64*65*4 = 32.5 KB.
// ---------------------------------------------------------------------------
__global__ __launch_bounds__(256) void tile_gather_gemm_kernel(
    const float* __restrict__ x,
    const float* __restrict__ WTrel,   // [F][F] k-major
    const float* __restrict__ b_rel,   // [F]
    const float* __restrict__ WTroot,  // [F][F] k-major
    const int* __restrict__ tileCnt,
    const unsigned* __restrict__ tileBuf,
    float* __restrict__ out, int n_nodes) {
  __shared__ float agg[TILE * PADR];
  __shared__ float xs[TILE * PADR];

  const int t = threadIdx.x;
  const int lane = t & 63;
  const int w = t >> 6;
  const int tile = blockIdx.x;
  const int node0 = tile * TILE;

  // zero the accumulator tile
  for (int i = t; i < TILE * PADR; i += 256) agg[i] = 0.0f;

  // stage the x self-tile (row-major)
  {
    const int r = t >> 2;             // 0..63
    const int c0 = (t & 3) * 16;      // 16 cols per thread
    const int gi = node0 + r;
#pragma unroll
    for (int c = 0; c < 16; c += 4) {
      float4 v = make_float4(0.f, 0.f, 0.f, 0.f);
      if (gi < n_nodes) v = *(const float4*)(x + (size_t)gi * F + c0 + c);
      xs[r * PADR + c0 + c + 0] = v.x;
      xs[r * PADR + c0 + c + 1] = v.y;
      xs[r * PADR + c0 + c + 2] = v.z;
      xs[r * PADR + c0 + c + 3] = v.w;
    }
  }
  __syncthreads();

  // ---- phase 1: lane-parallel scatter-accumulate into LDS
  const int cnt = min(tileCnt[tile * CNTP], CAP);
  const unsigned* lst = tileBuf + (size_t)tile * CAP;
  const int sub = lane >> 2;   // edge slot within a 16-edge group
  const int c0 = (lane & 3) * 16;  // this lane's 16-feature span

  for (int base = w * 64; base < cnt; base += 256) {
#pragma unroll
    for (int g = 0; g < 4; ++g) {
      const int ii = base + g * 16 + sub;
      const bool val = ii < cnt;
      const unsigned e = val ? lst[ii] : 0u;
      const int src = (int)(e & 0x1FFFFu);
      const int d = (int)(e >> 17);
      const float* xp = x + (size_t)src * F + c0;
      const float4 v0 = *(const float4*)(xp + 0);
      const float4 v1 = *(const float4*)(xp + 4);
      const float4 v2 = *(const float4*)(xp + 8);
      const float4 v3 = *(const float4*)(xp + 12);
      if (val) {
        float* ap = agg + d * PADR + c0;
        atomicAdd(ap + 0,  v0.x); atomicAdd(ap + 1,  v0.y);
        atomicAdd(ap + 2,  v0.z); atomicAdd(ap + 3,  v0.w);
        atomicAdd(ap + 4,  v1.x); atomicAdd(ap + 5,  v1.y);
        atomicAdd(ap + 6,  v1.z); atomicAdd(ap + 7,  v1.w);
        atomicAdd(ap + 8,  v2.x); atomicAdd(ap + 9,  v2.y);
        atomicAdd(ap + 10, v2.z); atomicAdd(ap + 11, v2.w);
        atomicAdd(ap + 12, v3.x); atomicAdd(ap + 13, v3.y);
        atomicAdd(ap + 14, v3.z); atomicAdd(ap + 15, v3.w);
      }
    }
  }
  __syncthreads();

  // ---- phase 2: out[r][o] = relu(b[o] + sum_k agg[r][k]*WTrel[k][o]
  //                                       + sum_k xs[r][k]*WTroot[k][o])
  const int oq = t & 15, rq = t >> 4;
  const int o0 = oq * 4, r0 = rq * 4;
  const float4 bias = *(const float4*)(b_rel + o0);
  float acc[4][4];
#pragma unroll
  for (int ri = 0; ri < 4; ++ri) {
    acc[ri][0] = bias.x; acc[ri][1] = bias.y;
    acc[ri][2] = bias.z; acc[ri][3] = bias.w;
  }
#pragma unroll 4
  for (int k = 0; k < F; ++k) {
    const float4 wr = *(const float4*)(WTrel + k * F + o0);
    const float4 wo = *(const float4*)(WTroot + k * F + o0);
    const float a0 = agg[(r0 + 0) * PADR + k], a1 = agg[(r0 + 1) * PADR + k];
    const float a2 = agg[(r0 + 2) * PADR + k], a3 = agg[(r0 + 3) * PADR + k];
    const float x0 = xs[(r0 + 0) * PADR + k], x1 = xs[(r0 + 1) * PADR + k];
    const float x2 = xs[(r0 + 2) * PADR + k], x3 = xs[(r0 + 3) * PADR + k];
    acc[0][0] += a0 * wr.x + x0 * wo.x; acc[0][1] += a0 * wr.y + x0 * wo.y;
    acc[0][2] += a0 * wr.z + x0 * wo.z; acc[0][3] += a0 * wr.w + x0 * wo.w;
    acc[1][0] += a1 * wr.x + x1 * wo.x; acc[1][1] += a1 * wr.y + x1 * wo.y;
    acc[1][2] += a1 * wr.z + x1 * wo.z; acc[1][3] += a1 * wr.w + x1 * wo.w;
    acc[2][0] += a2 * wr.x + x2 * wo.x; acc[2][1] += a2 * wr.y + x2 * wo.y;
    acc[2][2] += a2 * wr.z + x2 * wo.z; acc[2][3] += a2 * wr.w + x2 * wo.w;
    acc[3][0] += a3 * wr.x + x3 * wo.x; acc[3][1] += a3 * wr.y + x3 * wo.y;
    acc[3][2] += a3 * wr.z + x3 * wo.z; acc[3][3] += a3 * wr.w + x3 * wo.w;
  }
#pragma unroll
  for (int ri = 0; ri < 4; ++ri) {
    const int gi = node0 + r0 + ri;
    if (gi < n_nodes) {
      float4 o4;
      o4.x = fmaxf(acc[ri][0], 0.f); o4.y = fmaxf(acc[ri][1], 0.f);
      o4.z = fmaxf(acc[ri][2], 0.f); o4.w = fmaxf(acc[ri][3], 0.f);
      *(float4*)(out + (size_t)gi * F + o0) = o4;
    }
  }
}

extern "C" void kernel_launch(void* const* d_in, const int* in_sizes, int n_in,
                              void* d_out, int out_size, void* d_ws, size_t ws_size,
                              hipStream_t stream) {
  const float* x      = (const float*)d_in[0];  // [N, 64]
  const float* W_rel  = (const float*)d_in[1];  // [64, 64]
  const float* b_rel  = (const float*)d_in[2];  // [64]
  const float* W_root = (const float*)d_in[3];  // [64, 64]
  const int* edge_index = (const int*)d_in[4];  // [2, E]

  const int n_nodes = in_sizes[0] / F;
  const int n_edges = in_sizes[4] / 2;
  const int n_tiles = (n_nodes + TILE - 1) / TILE;  // 782

  // workspace: tileCnt[n_tiles*16] (50 KB) + tileBuf (6.4 MB) + WT (32 KB)
  int* tileCnt      = (int*)d_ws;
  unsigned* tileBuf = (unsigned*)(tileCnt + (size_t)n_tiles * CNTP);
  float* WTrel      = (float*)(tileBuf + (size_t)n_tiles * CAP);
  float* WTroot     = WTrel + F * F;

  float* out = (float*)d_out;

  hipMemsetAsync(tileCnt, 0, (size_t)n_tiles * CNTP * sizeof(int), stream);

  transpose_w_kernel<<<(F * F + 255) / 256, 256, 0, stream>>>(W_rel, W_root,
                                                              WTrel, WTroot);

  bin_kernel<<<(n_edges + 255) / 256, 256, 0, stream>>>(edge_index, tileCnt,
                                                        tileBuf, n_edges);

  tile_gather_gemm_kernel<<<n_tiles, 256, 0, stream>>>(
      x, WTrel, b_rel, WTroot, tileCnt, tileBuf, out, n_nodes);
}

// Round 6
// 179.712 us; speedup vs baseline: 3.5660x; 2.6304x over previous
//
#include <hip/hip_runtime.h>

#define F 64     // F_IN == F_OUT == 64
#define TILE 64  // nodes per tile / per fused block
#define CAP 2048 // bucket capacity (mean 1024 edges/tile, 32 sigma headroom)
#define PAD 65   // LDS row stride for k-major tiles
#define CNTP 16  // tileCnt padding: one counter per 64B line (R4 lesson)

// ---------------------------------------------------------------------------
// R5 -> R6: LDS float atomics were the wall (~275 cyc per ds_add_f32 wave
// instr = per-lane RMW serialization; R4/R5 both issued 1024/block -> both
// ~360 us despite different load structures).  R6: in-LDS counting sort of
// the tile bucket (int LDS atomics, only ~32 wave-instrs/block), then R3's
// proven atomic-free dense gather (4-deep float4 MLP + shfl_xor reduce).
// ---------------------------------------------------------------------------

// Bin edges by 64-node tile: entry = (dst&63)<<17 | src (src < 2^17).
__global__ __launch_bounds__(256) void bin_kernel(
    const int* __restrict__ edge_index, int* __restrict__ tileCnt,
    unsigned* __restrict__ tileBuf, int n_edges) {
  int e = blockIdx.x * 256 + threadIdx.x;
  if (e >= n_edges) return;
  int src = edge_index[e];
  int dst = edge_index[n_edges + e];
  int tile = dst >> 6;
  int pos = atomicAdd(&tileCnt[tile * CNTP], 1);
  if (pos < CAP)  // statistically never taken; guards OOB corruption
    tileBuf[(size_t)tile * CAP + pos] =
        ((unsigned)(dst & 63) << 17) | (unsigned)src;
}

// Transpose weights once: WT[k][o] = W[o][k] (32 KB, L1/L2-resident in GEMM).
__global__ __launch_bounds__(256) void transpose_w_kernel(
    const float* __restrict__ W_rel, const float* __restrict__ W_root,
    float* __restrict__ WTrel, float* __restrict__ WTroot) {
  int t = blockIdx.x * 256 + threadIdx.x;
  if (t < F * F) {
    int o = t >> 6, k = t & 63;
    WTrel[k * F + o] = W_rel[t];
    WTroot[k * F + o] = W_root[t];
  }
}

// ---------------------------------------------------------------------------
// Fused: in-LDS counting sort + dense gather + GEMM + bias + ReLU.
// Phases: 0) stage xT, zero hist, pad ssrc | A) dst histogram (int ds_add)
// B) 64-wide shfl exclusive scan | C) scatter srcs into sorted ssrc
// D) per-node gather: lanes = 4 edge-slots x 16 feature-quads; 4 LDS
//    broadcast src reads + 4 independent float4 x-gathers per 16 edges;
//    shfl_xor(16,32) slot reduce; slot-0 writes aggT k-major.  Zero float
//    atomics.
// E) GEMM: thread (rq,oq) owns 4x4 block; 8 ds_read + 2 L1 float4 + 32 FMA
//    per k.  LDS total ~42.5 KB -> 3 blocks/CU.
// ---------------------------------------------------------------------------
__global__ __launch_bounds__(256) void tile_sort_gather_gemm_kernel(
    const float* __restrict__ x,
    const float* __restrict__ WTrel,   // [F][F] k-major
    const float* __restrict__ b_rel,   // [F]
    const float* __restrict__ WTroot,  // [F][F] k-major
    const int* __restrict__ tileCnt,
    const unsigned* __restrict__ tileBuf,
    float* __restrict__ out, int n_nodes) {
  __shared__ float aggT[F * PAD];    // k-major: aggT[k*PAD + r]
  __shared__ float xT[F * PAD];      // k-major
  __shared__ int ssrc[CAP + 64];     // sorted-by-dst srcs (+64 zero pad)
  __shared__ int hist[TILE];
  __shared__ int soff[TILE + 1];
  __shared__ int scur[TILE];

  const int t = threadIdx.x;
  const int lane = t & 63;
  const int w = t >> 6;
  const int tile = blockIdx.x;
  const int node0 = tile * TILE;
  const int cnt = min(tileCnt[tile * CNTP], CAP);
  const unsigned* lst = tileBuf + (size_t)tile * CAP;

  // ---- phase 0: zero hist, pad ssrc tail, stage xT (k-major)
  if (t < TILE) hist[t] = 0;
  if (t < 64) ssrc[cnt + t] = 0;
  {
    const int c4 = t & 15;
    const int rr = t >> 4;
#pragma unroll
    for (int p = 0; p < 4; ++p) {
      const int r = p * 16 + rr;
      const int gi = node0 + r;
      float4 v = make_float4(0.f, 0.f, 0.f, 0.f);
      if (gi < n_nodes) v = *(const float4*)(x + (size_t)gi * F + c4 * 4);
      xT[(c4 * 4 + 0) * PAD + r] = v.x;
      xT[(c4 * 4 + 1) * PAD + r] = v.y;
      xT[(c4 * 4 + 2) * PAD + r] = v.z;
      xT[(c4 * 4 + 3) * PAD + r] = v.w;
    }
  }
  __syncthreads();

  // ---- phase A: histogram of local dsts (int LDS atomics, ~16 instrs)
  for (int i = t; i < cnt; i += 256) atomicAdd(&hist[lst[i] >> 17], 1);
  __syncthreads();

  // ---- phase B: exclusive scan of 64 counters (wave 0, shfl_up)
  if (w == 0) {
    int v = hist[lane];
    int incl = v;
#pragma unroll
    for (int d = 1; d < 64; d <<= 1) {
      int up = __shfl_up(incl, d, 64);
      if (lane >= d) incl += up;
    }
    soff[lane] = incl - v;
    scur[lane] = incl - v;
    if (lane == 63) soff[64] = incl;  // == cnt
  }
  __syncthreads();

  // ---- phase C: counting-sort scatter (int LDS atomics, ~16 instrs)
  for (int i = t; i < cnt; i += 256) {
    const unsigned e = lst[i];
    const int d = (int)(e >> 17);
    const int pos = atomicAdd(&scur[d], 1);
    ssrc[pos] = (int)(e & 0x1FFFFu);
  }
  __syncthreads();

  // ---- phase D: dense per-node gather (R3 structure, srcs from LDS)
  const int slot = lane >> 4;  // 0..3 edge slot
  const int fq = lane & 15;    // feature quad: features 4fq..4fq+3
  for (int nn = 0; nn < 16; ++nn) {
    const int d = w * 16 + nn;
    const int start = soff[d];
    const int end = soff[d + 1];
    float4 acc = make_float4(0.f, 0.f, 0.f, 0.f);
    for (int e0 = start; e0 < end; e0 += 64) {
      const int m = min(64, end - e0);
      for (int b = 0; b < m; b += 16) {
        const int i0 = b + slot, i1 = b + 4 + slot, i2 = b + 8 + slot,
                  i3 = b + 12 + slot;
        // LDS broadcast reads (4 consecutive dwords, 16-way broadcast each)
        const int s0 = ssrc[e0 + i0];
        const int s1 = ssrc[e0 + i1];
        const int s2 = ssrc[e0 + i2];
        const int s3 = ssrc[e0 + i3];
        // 4 independent float4 gathers in flight (pad srcs are 0 -> safe)
        const float4 f0 = *(const float4*)(x + (size_t)s0 * F + fq * 4);
        const float4 f1 = *(const float4*)(x + (size_t)s1 * F + fq * 4);
        const float4 f2 = *(const float4*)(x + (size_t)s2 * F + fq * 4);
        const float4 f3 = *(const float4*)(x + (size_t)s3 * F + fq * 4);
        acc.x += (i0 < m ? f0.x : 0.f); acc.y += (i0 < m ? f0.y : 0.f);
        acc.z += (i0 < m ? f0.z : 0.f); acc.w += (i0 < m ? f0.w : 0.f);
        acc.x += (i1 < m ? f1.x : 0.f); acc.y += (i1 < m ? f1.y : 0.f);
        acc.z += (i1 < m ? f1.z : 0.f); acc.w += (i1 < m ? f1.w : 0.f);
        acc.x += (i2 < m ? f2.x : 0.f); acc.y += (i2 < m ? f2.y : 0.f);
        acc.z += (i2 < m ? f2.z : 0.f); acc.w += (i2 < m ? f2.w : 0.f);
        acc.x += (i3 < m ? f3.x : 0.f); acc.y += (i3 < m ? f3.y : 0.f);
        acc.z += (i3 < m ? f3.z : 0.f); acc.w += (i3 < m ? f3.w : 0.f);
      }
    }
    // reduce the 4 slots
    acc.x += __shfl_xor(acc.x, 16, 64); acc.y += __shfl_xor(acc.y, 16, 64);
    acc.z += __shfl_xor(acc.z, 16, 64); acc.w += __shfl_xor(acc.w, 16, 64);
    acc.x += __shfl_xor(acc.x, 32, 64); acc.y += __shfl_xor(acc.y, 32, 64);
    acc.z += __shfl_xor(acc.z, 32, 64); acc.w += __shfl_xor(acc.w, 32, 64);
    if (slot == 0) {
      aggT[(fq * 4 + 0) * PAD + d] = acc.x;
      aggT[(fq * 4 + 1) * PAD + d] = acc.y;
      aggT[(fq * 4 + 2) * PAD + d] = acc.z;
      aggT[(fq * 4 + 3) * PAD + d] = acc.w;
    }
  }
  __syncthreads();

  // ---- phase E: out[r][o] = relu(b[o] + sum_k aggT[k][r]*WTrel[k][o]
  //                                       + sum_k xT[k][r]*WTroot[k][o])
  const int oq = t & 15, rq = t >> 4;
  const int o0 = oq * 4, r0 = rq * 4;
  const float4 bias = *(const float4*)(b_rel + o0);
  float acc[4][4];
#pragma unroll
  for (int ri = 0; ri < 4; ++ri) {
    acc[ri][0] = bias.x; acc[ri][1] = bias.y;
    acc[ri][2] = bias.z; acc[ri][3] = bias.w;
  }
#pragma unroll 4
  for (int k = 0; k < F; ++k) {
    const float4 wr = *(const float4*)(WTrel + k * F + o0);
    const float4 wo = *(const float4*)(WTroot + k * F + o0);
    const float a0 = aggT[k * PAD + r0 + 0], a1 = aggT[k * PAD + r0 + 1];
    const float a2 = aggT[k * PAD + r0 + 2], a3 = aggT[k * PAD + r0 + 3];
    const float x0 = xT[k * PAD + r0 + 0], x1 = xT[k * PAD + r0 + 1];
    const float x2 = xT[k * PAD + r0 + 2], x3 = xT[k * PAD + r0 + 3];
    acc[0][0] += a0 * wr.x + x0 * wo.x; acc[0][1] += a0 * wr.y + x0 * wo.y;
    acc[0][2] += a0 * wr.z + x0 * wo.z; acc[0][3] += a0 * wr.w + x0 * wo.w;
    acc[1][0] += a1 * wr.x + x1 * wo.x; acc[1][1] += a1 * wr.y + x1 * wo.y;
    acc[1][2] += a1 * wr.z + x1 * wo.z; acc[1][3] += a1 * wr.w + x1 * wo.w;
    acc[2][0] += a2 * wr.x + x2 * wo.x; acc[2][1] += a2 * wr.y + x2 * wo.y;
    acc[2][2] += a2 * wr.z + x2 * wo.z; acc[2][3] += a2 * wr.w + x2 * wo.w;
    acc[3][0] += a3 * wr.x + x3 * wo.x; acc[3][1] += a3 * wr.y + x3 * wo.y;
    acc[3][2] += a3 * wr.z + x3 * wo.z; acc[3][3] += a3 * wr.w + x3 * wo.w;
  }
#pragma unroll
  for (int ri = 0; ri < 4; ++ri) {
    const int gi = node0 + r0 + ri;
    if (gi < n_nodes) {
      float4 o4;
      o4.x = fmaxf(acc[ri][0], 0.f); o4.y = fmaxf(acc[ri][1], 0.f);
      o4.z = fmaxf(acc[ri][2], 0.f); o4.w = fmaxf(acc[ri][3], 0.f);
      *(float4*)(out + (size_t)gi * F + o0) = o4;
    }
  }
}

extern "C" void kernel_launch(void* const* d_in, const int* in_sizes, int n_in,
                              void* d_out, int out_size, void* d_ws, size_t ws_size,
                              hipStream_t stream) {
  const float* x      = (const float*)d_in[0];  // [N, 64]
  const float* W_rel  = (const float*)d_in[1];  // [64, 64]
  const float* b_rel  = (const float*)d_in[2];  // [64]
  const float* W_root = (const float*)d_in[3];  // [64, 64]
  const int* edge_index = (const int*)d_in[4];  // [2, E]

  const int n_nodes = in_sizes[0] / F;
  const int n_edges = in_sizes[4] / 2;
  const int n_tiles = (n_nodes + TILE - 1) / TILE;  // 782

  // workspace: tileCnt[n_tiles*16] (50 KB) + tileBuf (6.4 MB) + WT (32 KB)
  int* tileCnt      = (int*)d_ws;
  unsigned* tileBuf = (unsigned*)(tileCnt + (size_t)n_tiles * CNTP);
  float* WTrel      = (float*)(tileBuf + (size_t)n_tiles * CAP);
  float* WTroot     = WTrel + F * F;

  float* out = (float*)d_out;

  hipMemsetAsync(tileCnt, 0, (size_t)n_tiles * CNTP * sizeof(int), stream);

  transpose_w_kernel<<<(F * F + 255) / 256, 256, 0, stream>>>(W_rel, W_root,
                                                              WTrel, WTroot);

  bin_kernel<<<(n_edges + 255) / 256, 256, 0, stream>>>(edge_index, tileCnt,
                                                        tileBuf, n_edges);

  tile_sort_gather_gemm_kernel<<<n_tiles, 256, 0, stream>>>(
      x, WTrel, b_rel, WTroot, tileCnt, tileBuf, out, n_nodes);
}

// Round 7
// 148.167 us; speedup vs baseline: 4.3252x; 1.2129x over previous
//
#include <hip/hip_runtime.h>

#define F 64      // F_IN == F_OUT == 64
#define TILE 64   // nodes per tile / per fused block
#define CAP 2048  // bucket capacity (mean 1024 edges/tile, 32 sigma headroom)
#define PAD 65    // LDS row stride for k-major tiles
#define CNTP 16   // tileCnt padding: one counter per 64B line (R4 lesson)
#define NT_MAX 1024  // max tiles supported by bin kernel LDS tables
#define BIN_BLOCKS 128

// NOTE: this packing assumes n_nodes < 65536 (problem fixes N=50000).
// entry = dst<<16 | src ; tile = dst>>6 ; local d = (entry>>16)&63.

// ---------------------------------------------------------------------------
// R6 -> R7: (a) bin_kernel rewritten to kill the 16x write amplification —
// per-block LDS histogram reserves one contiguous region per (block,tile)
// with a single global atomicAdd, then entries are written densely into the
// region (whole 64B lines from one block/XCD; only boundary lines shared).
// Atomic count drops 800k -> ~100k.  (b) fused kernel: ssrc stored as
// ushort -> LDS 43 -> 38.3 KB -> 4 blocks/CU (occupancy +33%).
// ---------------------------------------------------------------------------
__global__ __launch_bounds__(256) void bin_kernel(
    const int* __restrict__ edge_index, int* __restrict__ tileCnt,
    unsigned* __restrict__ tileBuf, int n_edges, int n_tiles) {
  __shared__ int hist[NT_MAX];   // pass 1: counts; pass 2: local cursor
  __shared__ int gbase[NT_MAX];  // reserved global base per tile

  const int t = threadIdx.x;
  for (int i = t; i < n_tiles; i += 256) hist[i] = 0;
  __syncthreads();

  const int per = (n_edges + gridDim.x - 1) / gridDim.x;
  const int e0 = blockIdx.x * per;
  const int e1 = min(e0 + per, n_edges);

  // pass 1: histogram of this block's edge range by tile
  for (int e = e0 + t; e < e1; e += 256)
    atomicAdd(&hist[edge_index[n_edges + e] >> 6], 1);
  __syncthreads();

  // reserve contiguous regions (one global atomic per non-empty tile)
  for (int i = t; i < n_tiles; i += 256) {
    const int c = hist[i];
    gbase[i] = (c > 0) ? atomicAdd(&tileCnt[i * CNTP], c) : 0;
    hist[i] = 0;  // becomes the local cursor
  }
  __syncthreads();

  // pass 2: dense writes into the reserved regions
  for (int e = e0 + t; e < e1; e += 256) {
    const int src = edge_index[e];
    const int dst = edge_index[n_edges + e];
    const int tile = dst >> 6;
    const int pos = gbase[tile] + atomicAdd(&hist[tile], 1);
    if (pos < CAP)  // statistically never; guards bucket overflow corruption
      tileBuf[(size_t)tile * CAP + pos] =
          ((unsigned)dst << 16) | (unsigned)src;
  }
}

// Transpose weights once: WT[k][o] = W[o][k] (32 KB, L1/L2-resident in GEMM).
__global__ __launch_bounds__(256) void transpose_w_kernel(
    const float* __restrict__ W_rel, const float* __restrict__ W_root,
    float* __restrict__ WTrel, float* __restrict__ WTroot) {
  int t = blockIdx.x * 256 + threadIdx.x;
  if (t < F * F) {
    int o = t >> 6, k = t & 63;
    WTrel[k * F + o] = W_rel[t];
    WTroot[k * F + o] = W_root[t];
  }
}

// ---------------------------------------------------------------------------
// Fused: in-LDS counting sort + dense gather + GEMM + bias + ReLU.
// (R6 structure; ssrc now ushort -> 38.3 KB LDS -> 4 blocks/CU.)
// ---------------------------------------------------------------------------
__global__ __launch_bounds__(256) void tile_sort_gather_gemm_kernel(
    const float* __restrict__ x,
    const float* __restrict__ WTrel,   // [F][F] k-major
    const float* __restrict__ b_rel,   // [F]
    const float* __restrict__ WTroot,  // [F][F] k-major
    const int* __restrict__ tileCnt,
    const unsigned* __restrict__ tileBuf,
    float* __restrict__ out, int n_nodes) {
  __shared__ float aggT[F * PAD];           // k-major: aggT[k*PAD + r]
  __shared__ float xT[F * PAD];             // k-major
  __shared__ unsigned short ssrc[CAP + 64]; // sorted-by-dst srcs (+64 pad)
  __shared__ int hist[TILE];
  __shared__ int soff[TILE + 1];
  __shared__ int scur[TILE];

  const int t = threadIdx.x;
  const int lane = t & 63;
  const int w = t >> 6;
  const int tile = blockIdx.x;
  const int node0 = tile * TILE;
  const int cnt = min(tileCnt[tile * CNTP], CAP);
  const unsigned* lst = tileBuf + (size_t)tile * CAP;

  // ---- phase 0: zero hist, pad ssrc tail, stage xT (k-major)
  if (t < TILE) hist[t] = 0;
  if (t < 64) ssrc[cnt + t] = 0;
  {
    const int c4 = t & 15;
    const int rr = t >> 4;
#pragma unroll
    for (int p = 0; p < 4; ++p) {
      const int r = p * 16 + rr;
      const int gi = node0 + r;
      float4 v = make_float4(0.f, 0.f, 0.f, 0.f);
      if (gi < n_nodes) v = *(const float4*)(x + (size_t)gi * F + c4 * 4);
      xT[(c4 * 4 + 0) * PAD + r] = v.x;
      xT[(c4 * 4 + 1) * PAD + r] = v.y;
      xT[(c4 * 4 + 2) * PAD + r] = v.z;
      xT[(c4 * 4 + 3) * PAD + r] = v.w;
    }
  }
  __syncthreads();

  // ---- phase A: histogram of local dsts (int LDS atomics)
  for (int i = t; i < cnt; i += 256) atomicAdd(&hist[(lst[i] >> 16) & 63], 1);
  __syncthreads();

  // ---- phase B: exclusive scan of 64 counters (wave 0, shfl_up)
  if (w == 0) {
    int v = hist[lane];
    int incl = v;
#pragma unroll
    for (int d = 1; d < 64; d <<= 1) {
      int up = __shfl_up(incl, d, 64);
      if (lane >= d) incl += up;
    }
    soff[lane] = incl - v;
    scur[lane] = incl - v;
    if (lane == 63) soff[64] = incl;  // == cnt
  }
  __syncthreads();

  // ---- phase C: counting-sort scatter (int LDS atomics)
  for (int i = t; i < cnt; i += 256) {
    const unsigned e = lst[i];
    const int d = (int)((e >> 16) & 63);
    const int pos = atomicAdd(&scur[d], 1);
    ssrc[pos] = (unsigned short)(e & 0xFFFFu);
  }
  __syncthreads();

  // ---- phase D: dense per-node gather (atomic-free, 4-deep float4 MLP)
  const int slot = lane >> 4;  // 0..3 edge slot
  const int fq = lane & 15;    // feature quad: features 4fq..4fq+3
  for (int nn = 0; nn < 16; ++nn) {
    const int d = w * 16 + nn;
    const int start = soff[d];
    const int end = soff[d + 1];
    float4 acc = make_float4(0.f, 0.f, 0.f, 0.f);
    for (int e0 = start; e0 < end; e0 += 64) {
      const int m = min(64, end - e0);
      for (int b = 0; b < m; b += 16) {
        const int i0 = b + slot, i1 = b + 4 + slot, i2 = b + 8 + slot,
                  i3 = b + 12 + slot;
        // LDS broadcast reads (pad srcs are 0 -> loads safe)
        const int s0 = (int)ssrc[e0 + i0];
        const int s1 = (int)ssrc[e0 + i1];
        const int s2 = (int)ssrc[e0 + i2];
        const int s3 = (int)ssrc[e0 + i3];
        // 4 independent float4 gathers in flight
        const float4 f0 = *(const float4*)(x + (size_t)s0 * F + fq * 4);
        const float4 f1 = *(const float4*)(x + (size_t)s1 * F + fq * 4);
        const float4 f2 = *(const float4*)(x + (size_t)s2 * F + fq * 4);
        const float4 f3 = *(const float4*)(x + (size_t)s3 * F + fq * 4);
        acc.x += (i0 < m ? f0.x : 0.f); acc.y += (i0 < m ? f0.y : 0.f);
        acc.z += (i0 < m ? f0.z : 0.f); acc.w += (i0 < m ? f0.w : 0.f);
        acc.x += (i1 < m ? f1.x : 0.f); acc.y += (i1 < m ? f1.y : 0.f);
        acc.z += (i1 < m ? f1.z : 0.f); acc.w += (i1 < m ? f1.w : 0.f);
        acc.x += (i2 < m ? f2.x : 0.f); acc.y += (i2 < m ? f2.y : 0.f);
        acc.z += (i2 < m ? f2.z : 0.f); acc.w += (i2 < m ? f2.w : 0.f);
        acc.x += (i3 < m ? f3.x : 0.f); acc.y += (i3 < m ? f3.y : 0.f);
        acc.z += (i3 < m ? f3.z : 0.f); acc.w += (i3 < m ? f3.w : 0.f);
      }
    }
    // reduce the 4 slots
    acc.x += __shfl_xor(acc.x, 16, 64); acc.y += __shfl_xor(acc.y, 16, 64);
    acc.z += __shfl_xor(acc.z, 16, 64); acc.w += __shfl_xor(acc.w, 16, 64);
    acc.x += __shfl_xor(acc.x, 32, 64); acc.y += __shfl_xor(acc.y, 32, 64);
    acc.z += __shfl_xor(acc.z, 32, 64); acc.w += __shfl_xor(acc.w, 32, 64);
    if (slot == 0) {
      aggT[(fq * 4 + 0) * PAD + d] = acc.x;
      aggT[(fq * 4 + 1) * PAD + d] = acc.y;
      aggT[(fq * 4 + 2) * PAD + d] = acc.z;
      aggT[(fq * 4 + 3) * PAD + d] = acc.w;
    }
  }
  __syncthreads();

  // ---- phase E: out[r][o] = relu(b[o] + sum_k aggT[k][r]*WTrel[k][o]
  //                                       + sum_k xT[k][r]*WTroot[k][o])
  const int oq = t & 15, rq = t >> 4;
  const int o0 = oq * 4, r0 = rq * 4;
  const float4 bias = *(const float4*)(b_rel + o0);
  float acc[4][4];
#pragma unroll
  for (int ri = 0; ri < 4; ++ri) {
    acc[ri][0] = bias.x; acc[ri][1] = bias.y;
    acc[ri][2] = bias.z; acc[ri][3] = bias.w;
  }
#pragma unroll 4
  for (int k = 0; k < F; ++k) {
    const float4 wr = *(const float4*)(WTrel + k * F + o0);
    const float4 wo = *(const float4*)(WTroot + k * F + o0);
    const float a0 = aggT[k * PAD + r0 + 0], a1 = aggT[k * PAD + r0 + 1];
    const float a2 = aggT[k * PAD + r0 + 2], a3 = aggT[k * PAD + r0 + 3];
    const float x0 = xT[k * PAD + r0 + 0], x1 = xT[k * PAD + r0 + 1];
    const float x2 = xT[k * PAD + r0 + 2], x3 = xT[k * PAD + r0 + 3];
    acc[0][0] += a0 * wr.x + x0 * wo.x; acc[0][1] += a0 * wr.y + x0 * wo.y;
    acc[0][2] += a0 * wr.z + x0 * wo.z; acc[0][3] += a0 * wr.w + x0 * wo.w;
    acc[1][0] += a1 * wr.x + x1 * wo.x; acc[1][1] += a1 * wr.y + x1 * wo.y;
    acc[1][2] += a1 * wr.z + x1 * wo.z; acc[1][3] += a1 * wr.w + x1 * wo.w;
    acc[2][0] += a2 * wr.x + x2 * wo.x; acc[2][1] += a2 * wr.y + x2 * wo.y;
    acc[2][2] += a2 * wr.z + x2 * wo.z; acc[2][3] += a2 * wr.w + x2 * wo.w;
    acc[3][0] += a3 * wr.x + x3 * wo.x; acc[3][1] += a3 * wr.y + x3 * wo.y;
    acc[3][2] += a3 * wr.z + x3 * wo.z; acc[3][3] += a3 * wr.w + x3 * wo.w;
  }
#pragma unroll
  for (int ri = 0; ri < 4; ++ri) {
    const int gi = node0 + r0 + ri;
    if (gi < n_nodes) {
      float4 o4;
      o4.x = fmaxf(acc[ri][0], 0.f); o4.y = fmaxf(acc[ri][1], 0.f);
      o4.z = fmaxf(acc[ri][2], 0.f); o4.w = fmaxf(acc[ri][3], 0.f);
      *(float4*)(out + (size_t)gi * F + o0) = o4;
    }
  }
}

extern "C" void kernel_launch(void* const* d_in, const int* in_sizes, int n_in,
                              void* d_out, int out_size, void* d_ws, size_t ws_size,
                              hipStream_t stream) {
  const float* x      = (const float*)d_in[0];  // [N, 64]
  const float* W_rel  = (const float*)d_in[1];  // [64, 64]
  const float* b_rel  = (const float*)d_in[2];  // [64]
  const float* W_root = (const float*)d_in[3];  // [64, 64]
  const int* edge_index = (const int*)d_in[4];  // [2, E]

  const int n_nodes = in_sizes[0] / F;
  const int n_edges = in_sizes[4] / 2;
  const int n_tiles = (n_nodes + TILE - 1) / TILE;  // 782

  // workspace: tileCnt[n_tiles*16] (50 KB) + tileBuf (6.4 MB) + WT (32 KB)
  int* tileCnt      = (int*)d_ws;
  unsigned* tileBuf = (unsigned*)(tileCnt + (size_t)n_tiles * CNTP);
  float* WTrel      = (float*)(tileBuf + (size_t)n_tiles * CAP);
  float* WTroot     = WTrel + F * F;

  float* out = (float*)d_out;

  hipMemsetAsync(tileCnt, 0, (size_t)n_tiles * CNTP * sizeof(int), stream);

  transpose_w_kernel<<<(F * F + 255) / 256, 256, 0, stream>>>(W_rel, W_root,
                                                              WTrel, WTroot);

  bin_kernel<<<BIN_BLOCKS, 256, 0, stream>>>(edge_index, tileCnt, tileBuf,
                                             n_edges, n_tiles);

  tile_sort_gather_gemm_kernel<<<n_tiles, 256, 0, stream>>>(
      x, WTrel, b_rel, WTroot, tileCnt, tileBuf, out, n_nodes);
}